// Round 7
// baseline (157.194 us; speedup 1.0000x reference)
//
#include <hip/hip_runtime.h>
#include <hip/hip_bf16.h>

// HeteroLinear: out[b,n,o] = sum_i x[b,n,i] * W[t[n]][o][i] + bias[t[n]][o]
// B=16, N=16384, F_IN=F_OUT=128, NUM_TYPES=16, fp32 in/out.
//
// Round 7: back to R4's 8-wave blocks (best measured; R6's 4-wave variant
// cut machine TLP 4x). New: (a) scatter emits a padded packed per-slot
// table porder[blk*16+slot] = (t<<20)|invalid<<16|n — main wave start is
// ONE independent L2 load instead of a 3-deep probe/offset/order chain;
// (b) NPB=16 = 8 waves x 2 nodes serial: W staging + startup amortized 2x,
// node-1 x loads overlap node-0 MFMA. Accuracy: x hi/lo bf16 split, W bf16.

#define NN 16384
#define FF 128
#define NT 16
#define NPB 16           // nodes per main block (8 waves x 2 nodes)
#define NBLK (NN / NPB + NT)          // 1040 (upper bound on real blocks)
#define PB 64            // prep blocks
#define WS_PORD 64
#define WS_BH (WS_PORD + NBLK * NPB)  // per-(type,block) hist region

typedef __bf16 bf16x8 __attribute__((ext_vector_type(8)));
typedef float  f32x4  __attribute__((ext_vector_type(4)));

// ws int layout: [48] = #real blocks; [WS_PORD : WS_PORD+NBLK*NPB) packed
// node table; [WS_BH : WS_BH+NT*PB) per-block hist.

__global__ __launch_bounds__(256) void hl_hist(const int* __restrict__ tv,
                                               int* __restrict__ ws) {
    __shared__ int wh[4][NT];
    const int tid = threadIdx.x, lane = tid & 63, wv = tid >> 6;
    const int t = tv[blockIdx.x * 256 + tid];
#pragma unroll
    for (int ty = 0; ty < NT; ++ty) {
        const unsigned long long m = __ballot(t == ty);
        if (lane == 0) wh[wv][ty] = __popcll(m);
    }
    __syncthreads();
    if (tid < NT)
        ws[WS_BH + tid * PB + blockIdx.x] = wh[0][tid] + wh[1][tid] + wh[2][tid] + wh[3][tid];
}

__global__ __launch_bounds__(256) void hl_scatter(const int* __restrict__ tv,
                                                  int* __restrict__ ws) {
    __shared__ int bh[NT * PB];
    __shared__ int scnt[NT], mybase[NT], sblk[NT + 1];
    __shared__ int wh[4][NT], wbase[4][NT];
    const int tid = threadIdx.x, lane = tid & 63, wv = tid >> 6;

    for (int i = tid; i < NT * PB; i += 256) bh[i] = ws[WS_BH + i];

    const int n = blockIdx.x * 256 + tid;
    const int t = tv[n];
    int myrank = 0;
#pragma unroll
    for (int ty = 0; ty < NT; ++ty) {
        const unsigned long long m = __ballot(t == ty);
        if (lane == 0) wh[wv][ty] = __popcll(m);
        if (t == ty) myrank = __popcll(m & ((1ull << lane) - 1ull));
    }
    __syncthreads();
    if (tid < NT) {                 // per-type: global count + my block's base
        int acc = 0, myb = 0;
        for (int b = 0; b < PB; ++b) {
            if (b == (int)blockIdx.x) myb = acc;
            acc += bh[tid * PB + b];
        }
        scnt[tid] = acc;
        mybase[tid] = myb;
    }
    __syncthreads();
    if (tid == 0) {                 // padded block offsets per type
        int bacc = 0;
        for (int ty = 0; ty < NT; ++ty) {
            sblk[ty] = bacc;
            bacc += (scnt[ty] + NPB - 1) / NPB;
        }
        sblk[NT] = bacc;
        if (blockIdx.x == 0) ws[48] = bacc;
    }
    __syncthreads();
    if (tid < NT) {
        int base = sblk[tid] * NPB + mybase[tid];
        for (int w = 0; w < 4; ++w) { wbase[w][tid] = base; base += wh[w][tid]; }
    }
    __syncthreads();
    ws[WS_PORD + wbase[wv][t] + myrank] = (t << 20) | n;     // valid entry

    if (blockIdx.x == 0 && tid < NT) {                       // typed sentinels
        const int lo = sblk[tid] * NPB + scnt[tid];
        const int hi = sblk[tid + 1] * NPB;
        for (int s = lo; s < hi; ++s) ws[WS_PORD + s] = (tid << 20) | 0x10000;
    }
}

__device__ __forceinline__ void cvt_split(const f32x4 xv[8], bf16x8 ahi[4],
                                          bf16x8 alo[4]) {
#pragma unroll
    for (int kk = 0; kk < 4; ++kk) {
#pragma unroll
        for (int j = 0; j < 4; ++j) {
            const float f0 = xv[2 * kk][j], f1 = xv[2 * kk + 1][j];
            const __bf16 h0 = (__bf16)f0, h1 = (__bf16)f1;
            ahi[kk][j]     = h0;  alo[kk][j]     = (__bf16)(f0 - (float)h0);
            ahi[kk][4 + j] = h1;  alo[kk][4 + j] = (__bf16)(f1 - (float)h1);
        }
    }
}

__device__ __forceinline__ void node_compute(const bf16x8 ahi[4], const bf16x8 alo[4],
                                             const unsigned char* Wl, const float bv[8],
                                             int n, bool valid, float* __restrict__ out,
                                             int lrow, int lgrp) {
    f32x4 acc[8];
#pragma unroll
    for (int ot = 0; ot < 8; ++ot) acc[ot] = (f32x4){0.f, 0.f, 0.f, 0.f};
#pragma unroll
    for (int kk = 0; kk < 4; ++kk) {
#pragma unroll
        for (int ot = 0; ot < 8; ++ot) {
            const int o  = ot * 16 + lrow;
            const int cb = (kk * 64 + lgrp * 16) ^ ((o & 7) << 4);
            const bf16x8 wf = *(const bf16x8*)(Wl + o * 256 + cb);
            acc[ot] = __builtin_amdgcn_mfma_f32_16x16x32_bf16(ahi[kk], wf, acc[ot], 0, 0, 0);
            acc[ot] = __builtin_amdgcn_mfma_f32_16x16x32_bf16(alo[kk], wf, acc[ot], 0, 0, 0);
        }
    }
    if (valid) {
#pragma unroll
        for (int ot = 0; ot < 8; ++ot) {
            const int o = ot * 16 + lrow;
#pragma unroll
            for (int r = 0; r < 4; ++r) {
                out[(size_t)(lgrp * 4 + r) * ((size_t)NN * FF) + (size_t)n * FF + o]
                    = acc[ot][r] + bv[ot];
            }
        }
    }
}

__global__ __launch_bounds__(512, 4) void hl_main(
    const float* __restrict__ x,      // [16][NN][128]
    const float* __restrict__ W,      // [16][128][128]
    const float* __restrict__ bias,   // [16][128]
    const int*   __restrict__ ws,
    float*       __restrict__ out)    // [16][NN][128]
{
    const int lane = threadIdx.x & 63;
    const int wv   = threadIdx.x >> 6;   // 0..7
    const int bid  = blockIdx.x;

    // one independent load per node slot — no dependent chain
    const int e0 = ws[WS_PORD + bid * NPB + wv];
    const int e1 = ws[WS_PORD + bid * NPB + 8 + wv];
    if (bid >= ws[48]) return;

    const int  t  = e0 >> 20;
    const bool v0 = !(e0 & 0x10000), v1 = !(e1 & 0x10000);
    const int  n0 = e0 & 0x3FFF,     n1 = e1 & 0x3FFF;

    const int lrow = lane & 15;   // A row (b) / B col (o) / D col (o)
    const int lgrp = lane >> 4;   // k-group of 8 / D row-group

    const float* xbase = x + (size_t)lrow * ((size_t)NN * FF) + lgrp * 8;

    // node-0 x loads in flight under W staging
    f32x4 xv0[8];
#pragma unroll
    for (int kk = 0; kk < 4; ++kk) {
        const float* xp = xbase + (size_t)n0 * FF + kk * 32;
        xv0[2 * kk]     = *(const f32x4*)xp;
        xv0[2 * kk + 1] = *(const f32x4*)(xp + 4);
    }

    float bv[8];
#pragma unroll
    for (int ot = 0; ot < 8; ++ot) bv[ot] = bias[t * FF + ot * 16 + lrow];

    // stage W[t] as bf16 [o][k], 256B/row, XOR-swizzled 16B slots
    __shared__ __align__(16) unsigned char Wl[FF * 256];
    const float* Wt = W + t * (FF * FF);
#pragma unroll
    for (int ii = 0; ii < 4; ++ii) {
        const int idx = ii * 512 + threadIdx.x;
        const float* p = Wt + idx * 8;
        f32x4 a = *(const f32x4*)p;
        f32x4 b = *(const f32x4*)(p + 4);
        bf16x8 v;
#pragma unroll
        for (int j = 0; j < 4; ++j) { v[j] = (__bf16)a[j]; v[4 + j] = (__bf16)b[j]; }
        const int o  = idx >> 4;
        const int cb = (idx & 15) << 4;
        *(bf16x8*)(Wl + o * 256 + (cb ^ ((o & 7) << 4))) = v;
    }
    __syncthreads();

    // node 0: convert (frees xv0) -> issue node-1 x loads -> MFMA+store
    bf16x8 ahi0[4], alo0[4];
    cvt_split(xv0, ahi0, alo0);

    f32x4 xv1[8];
#pragma unroll
    for (int kk = 0; kk < 4; ++kk) {
        const float* xp = xbase + (size_t)n1 * FF + kk * 32;
        xv1[2 * kk]     = *(const f32x4*)xp;
        xv1[2 * kk + 1] = *(const f32x4*)(xp + 4);
    }

    node_compute(ahi0, alo0, Wl, bv, n0, v0, out, lrow, lgrp);

    // node 1
    bf16x8 ahi1[4], alo1[4];
    cvt_split(xv1, ahi1, alo1);
    node_compute(ahi1, alo1, Wl, bv, n1, v1, out, lrow, lgrp);
}

extern "C" void kernel_launch(void* const* d_in, const int* in_sizes, int n_in,
                              void* d_out, int out_size, void* d_ws, size_t ws_size,
                              hipStream_t stream) {
    const float* x    = (const float*)d_in[0];
    const int*   tv   = (const int*)d_in[1];
    const float* W    = (const float*)d_in[2];
    const float* bias = (const float*)d_in[3];
    float*       out  = (float*)d_out;
    int*         wsI  = (int*)d_ws;

    hl_hist<<<PB, 256, 0, stream>>>(tv, wsI);
    hl_scatter<<<PB, 256, 0, stream>>>(tv, wsI);
    hl_main<<<NBLK, 512, 0, stream>>>(x, W, bias, wsI, out);
}

// Round 8
// 71.665 us; speedup vs baseline: 2.1934x; 2.1934x over previous
//
#include <hip/hip_runtime.h>
#include <hip/hip_bf16.h>

// HeteroLinear: out[b,n,o] = sum_i x[b,n,i] * W[t[n]][o][i] + bias[t[n]][o]
// B=16, N=16384, F_IN=F_OUT=128, NUM_TYPES=16, fp32 in/out.
//
// Round 8: R7's structure (porder single-load header + 8 waves x 2 nodes)
// but FULLY INLINED — R7's helper functions took fragment arrays as
// pointer params, defeating SROA: arrays went to scratch (VGPR 64,
// FETCH+105MB/WRITE+196MB of spill traffic, 87->157us). All loops use
// compile-time indices; sched_barrier(0) pins node-1 x prefetch before
// node-0's MFMA cluster so the compiler can't sink it (R6: prefetch
// sunk, VGPR 52, no overlap).

#define NN 16384
#define FF 128
#define NT 16
#define NPB 16           // nodes per main block (8 waves x 2 nodes)
#define NBLK (NN / NPB + NT)          // 1040 (upper bound on real blocks)
#define PB 64            // prep blocks
#define WS_PORD 64
#define WS_BH (WS_PORD + NBLK * NPB)  // per-(type,block) hist region

typedef __bf16 bf16x8 __attribute__((ext_vector_type(8)));
typedef float  f32x4  __attribute__((ext_vector_type(4)));

// ws int layout: [48] = #real blocks; [WS_PORD : WS_PORD+NBLK*NPB) packed
// node table (t<<20 | invalid<<16 | n); [WS_BH : WS_BH+NT*PB) hist.

__global__ __launch_bounds__(256) void hl_hist(const int* __restrict__ tv,
                                               int* __restrict__ ws) {
    __shared__ int wh[4][NT];
    const int tid = threadIdx.x, lane = tid & 63, wv = tid >> 6;
    const int t = tv[blockIdx.x * 256 + tid];
#pragma unroll
    for (int ty = 0; ty < NT; ++ty) {
        const unsigned long long m = __ballot(t == ty);
        if (lane == 0) wh[wv][ty] = __popcll(m);
    }
    __syncthreads();
    if (tid < NT)
        ws[WS_BH + tid * PB + blockIdx.x] = wh[0][tid] + wh[1][tid] + wh[2][tid] + wh[3][tid];
}

__global__ __launch_bounds__(256) void hl_scatter(const int* __restrict__ tv,
                                                  int* __restrict__ ws) {
    __shared__ int bh[NT * PB];
    __shared__ int scnt[NT], mybase[NT], sblk[NT + 1];
    __shared__ int wh[4][NT], wbase[4][NT];
    const int tid = threadIdx.x, lane = tid & 63, wv = tid >> 6;

    for (int i = tid; i < NT * PB; i += 256) bh[i] = ws[WS_BH + i];

    const int n = blockIdx.x * 256 + tid;
    const int t = tv[n];
    int myrank = 0;
#pragma unroll
    for (int ty = 0; ty < NT; ++ty) {
        const unsigned long long m = __ballot(t == ty);
        if (lane == 0) wh[wv][ty] = __popcll(m);
        if (t == ty) myrank = __popcll(m & ((1ull << lane) - 1ull));
    }
    __syncthreads();
    if (tid < NT) {                 // per-type: global count + my block's base
        int acc = 0, myb = 0;
        for (int b = 0; b < PB; ++b) {
            if (b == (int)blockIdx.x) myb = acc;
            acc += bh[tid * PB + b];
        }
        scnt[tid] = acc;
        mybase[tid] = myb;
    }
    __syncthreads();
    if (tid == 0) {                 // padded block offsets per type
        int bacc = 0;
        for (int ty = 0; ty < NT; ++ty) {
            sblk[ty] = bacc;
            bacc += (scnt[ty] + NPB - 1) / NPB;
        }
        sblk[NT] = bacc;
        if (blockIdx.x == 0) ws[48] = bacc;
    }
    __syncthreads();
    if (tid < NT) {
        int base = sblk[tid] * NPB + mybase[tid];
        for (int w = 0; w < 4; ++w) { wbase[w][tid] = base; base += wh[w][tid]; }
    }
    __syncthreads();
    ws[WS_PORD + wbase[wv][t] + myrank] = (t << 20) | n;     // valid entry

    if (blockIdx.x == 0 && tid < NT) {                       // typed sentinels
        const int lo = sblk[tid] * NPB + scnt[tid];
        const int hi = sblk[tid + 1] * NPB;
        for (int s = lo; s < hi; ++s) ws[WS_PORD + s] = (tid << 20) | 0x10000;
    }
}

__global__ __launch_bounds__(512, 4) void hl_main(
    const float* __restrict__ x,      // [16][NN][128]
    const float* __restrict__ W,      // [16][128][128]
    const float* __restrict__ bias,   // [16][128]
    const int*   __restrict__ ws,
    float*       __restrict__ out)    // [16][NN][128]
{
    const int lane = threadIdx.x & 63;
    const int wv   = threadIdx.x >> 6;   // 0..7
    const int bid  = blockIdx.x;

    // one independent load per node slot — no dependent chain
    const int e0 = ws[WS_PORD + bid * NPB + wv];
    const int e1 = ws[WS_PORD + bid * NPB + 8 + wv];
    if (bid >= ws[48]) return;

    const int  t  = e0 >> 20;
    const bool v0 = !(e0 & 0x10000), v1 = !(e1 & 0x10000);
    const int  n0 = e0 & 0x3FFF,     n1 = e1 & 0x3FFF;

    const int lrow = lane & 15;   // A row (b) / B col (o) / D col (o)
    const int lgrp = lane >> 4;   // k-group of 8 / D row-group

    const float* xbase = x + (size_t)lrow * ((size_t)NN * FF) + lgrp * 8;

    // node-0 x loads in flight under W staging
    f32x4 xv0[8];
#pragma unroll
    for (int kk = 0; kk < 4; ++kk) {
        const float* xp = xbase + (size_t)n0 * FF + kk * 32;
        xv0[2 * kk]     = *(const f32x4*)xp;
        xv0[2 * kk + 1] = *(const f32x4*)(xp + 4);
    }

    float bv[8];
#pragma unroll
    for (int ot = 0; ot < 8; ++ot) bv[ot] = bias[t * FF + ot * 16 + lrow];

    // stage W[t] as bf16 [o][k], 256B/row, XOR-swizzled 16B slots
    __shared__ __align__(16) unsigned char Wl[FF * 256];
    const float* Wt = W + t * (FF * FF);
#pragma unroll
    for (int ii = 0; ii < 4; ++ii) {
        const int idx = ii * 512 + threadIdx.x;
        const float* p = Wt + idx * 8;
        f32x4 a = *(const f32x4*)p;
        f32x4 b = *(const f32x4*)(p + 4);
        bf16x8 v;
#pragma unroll
        for (int j = 0; j < 4; ++j) { v[j] = (__bf16)a[j]; v[4 + j] = (__bf16)b[j]; }
        const int o  = idx >> 4;
        const int cb = (idx & 15) << 4;
        *(bf16x8*)(Wl + o * 256 + (cb ^ ((o & 7) << 4))) = v;
    }
    __syncthreads();

    // ---- node 0: convert (consumes xv0) ----
    bf16x8 ahi0[4], alo0[4];
#pragma unroll
    for (int kk = 0; kk < 4; ++kk) {
#pragma unroll
        for (int j = 0; j < 4; ++j) {
            const float f0 = xv0[2 * kk][j], f1 = xv0[2 * kk + 1][j];
            const __bf16 h0 = (__bf16)f0, h1 = (__bf16)f1;
            ahi0[kk][j]     = h0;  alo0[kk][j]     = (__bf16)(f0 - (float)h0);
            ahi0[kk][4 + j] = h1;  alo0[kk][4 + j] = (__bf16)(f1 - (float)h1);
        }
    }

    // ---- issue node-1 x loads NOW; pin them above node-0's MFMAs ----
    f32x4 xv1[8];
#pragma unroll
    for (int kk = 0; kk < 4; ++kk) {
        const float* xp = xbase + (size_t)n1 * FF + kk * 32;
        xv1[2 * kk]     = *(const f32x4*)xp;
        xv1[2 * kk + 1] = *(const f32x4*)(xp + 4);
    }
    __builtin_amdgcn_sched_barrier(0);

    // ---- node 0: MFMA + store ----
    f32x4 acc[8];
#pragma unroll
    for (int ot = 0; ot < 8; ++ot) acc[ot] = (f32x4){0.f, 0.f, 0.f, 0.f};
#pragma unroll
    for (int kk = 0; kk < 4; ++kk) {
#pragma unroll
        for (int ot = 0; ot < 8; ++ot) {
            const int o  = ot * 16 + lrow;
            const int cb = (kk * 64 + lgrp * 16) ^ ((o & 7) << 4);
            const bf16x8 wf = *(const bf16x8*)(Wl + o * 256 + cb);
            acc[ot] = __builtin_amdgcn_mfma_f32_16x16x32_bf16(ahi0[kk], wf, acc[ot], 0, 0, 0);
            acc[ot] = __builtin_amdgcn_mfma_f32_16x16x32_bf16(alo0[kk], wf, acc[ot], 0, 0, 0);
        }
    }
    if (v0) {
#pragma unroll
        for (int ot = 0; ot < 8; ++ot) {
            const int o = ot * 16 + lrow;
#pragma unroll
            for (int r = 0; r < 4; ++r) {
                out[(size_t)(lgrp * 4 + r) * ((size_t)NN * FF) + (size_t)n0 * FF + o]
                    = acc[ot][r] + bv[ot];
            }
        }
    }

    // ---- node 1: convert + MFMA + store ----
    bf16x8 ahi1[4], alo1[4];
#pragma unroll
    for (int kk = 0; kk < 4; ++kk) {
#pragma unroll
        for (int j = 0; j < 4; ++j) {
            const float f0 = xv1[2 * kk][j], f1 = xv1[2 * kk + 1][j];
            const __bf16 h0 = (__bf16)f0, h1 = (__bf16)f1;
            ahi1[kk][j]     = h0;  alo1[kk][j]     = (__bf16)(f0 - (float)h0);
            ahi1[kk][4 + j] = h1;  alo1[kk][4 + j] = (__bf16)(f1 - (float)h1);
        }
    }
#pragma unroll
    for (int ot = 0; ot < 8; ++ot) acc[ot] = (f32x4){0.f, 0.f, 0.f, 0.f};
#pragma unroll
    for (int kk = 0; kk < 4; ++kk) {
#pragma unroll
        for (int ot = 0; ot < 8; ++ot) {
            const int o  = ot * 16 + lrow;
            const int cb = (kk * 64 + lgrp * 16) ^ ((o & 7) << 4);
            const bf16x8 wf = *(const bf16x8*)(Wl + o * 256 + cb);
            acc[ot] = __builtin_amdgcn_mfma_f32_16x16x32_bf16(ahi1[kk], wf, acc[ot], 0, 0, 0);
            acc[ot] = __builtin_amdgcn_mfma_f32_16x16x32_bf16(alo1[kk], wf, acc[ot], 0, 0, 0);
        }
    }
    if (v1) {
#pragma unroll
        for (int ot = 0; ot < 8; ++ot) {
            const int o = ot * 16 + lrow;
#pragma unroll
            for (int r = 0; r < 4; ++r) {
                out[(size_t)(lgrp * 4 + r) * ((size_t)NN * FF) + (size_t)n1 * FF + o]
                    = acc[ot][r] + bv[ot];
            }
        }
    }
}

extern "C" void kernel_launch(void* const* d_in, const int* in_sizes, int n_in,
                              void* d_out, int out_size, void* d_ws, size_t ws_size,
                              hipStream_t stream) {
    const float* x    = (const float*)d_in[0];
    const int*   tv   = (const int*)d_in[1];
    const float* W    = (const float*)d_in[2];
    const float* bias = (const float*)d_in[3];
    float*       out  = (float*)d_out;
    int*         wsI  = (int*)d_ws;

    hl_hist<<<PB, 256, 0, stream>>>(tv, wsI);
    hl_scatter<<<PB, 256, 0, stream>>>(tv, wsI);
    hl_main<<<NBLK, 512, 0, stream>>>(x, W, bias, wsI, out);
}